// Round 1
// baseline (221.871 us; speedup 1.0000x reference)
//
#include <hip/hip_runtime.h>

constexpr int NB = 8;
constexpr int NN = 8192;
constexpr int NH = 128;
constexpr int NG = 16;
constexpr float EPS = 1e-8f;

__device__ __forceinline__ float frcp(float x) { return __builtin_amdgcn_rcpf(x); }
__device__ __forceinline__ float fsqrt(float x) { return __builtin_amdgcn_sqrtf(x); }
__device__ __forceinline__ float fsigmoid(float x) { return frcp(1.f + __expf(-x)); }
__device__ __forceinline__ float fsilu(float x) { return x * fsigmoid(x); }
__device__ __forceinline__ float fclamp1(float x) { return fminf(fmaxf(x, -1.f), 1.f); }

// ---------------- K1: vec_geom = vec @ W_geom  (B*N*3, H) @ (H, G) ----------
__global__ __launch_bounds__(256) void k_vecgeom(const float* __restrict__ vec,
                                                 const float* __restrict__ Wg,
                                                 float* __restrict__ vg) {
    __shared__ float Wl[NH * NG];
    for (int t = threadIdx.x; t < NH * NG; t += 256) Wl[t] = Wg[t];
    __syncthreads();

    int idx = blockIdx.x * 256 + threadIdx.x;   // 0 .. B*N*48  (exact grid)
    int node = idx / 48;                        // b*N + n
    int cg = idx % 48;
    int c = cg >> 4, g = cg & 15;
    const float* vrow = vec + (node * 3 + c) * NH;
    float acc = 0.f;
#pragma unroll 8
    for (int h = 0; h < NH; h += 4) {
        float4 v4 = *reinterpret_cast<const float4*>(vrow + h);
        acc = fmaf(v4.x, Wl[(h + 0) * NG + g], acc);
        acc = fmaf(v4.y, Wl[(h + 1) * NG + g], acc);
        acc = fmaf(v4.z, Wl[(h + 2) * NG + g], acc);
        acc = fmaf(v4.w, Wl[(h + 3) * NG + g], acc);
    }
    vg[(node * 3 + c) * NG + g] = acc;
}

// ---------------- K2: u[i] = sum_j normalize(vg[j]-vg[i]) -------------------
__global__ __launch_bounds__(256) void k_u(const float* __restrict__ vg,
                                           float* __restrict__ u) {
    int idx = blockIdx.x * 256 + threadIdx.x;   // 0 .. B*N*16 (exact grid)
    int g = idx & 15;
    int bn = idx >> 4;                          // b*N + n
    int n = bn & (NN - 1);
    int base_i = (bn * 3) * NG + g;
    float vi0 = vg[base_i], vi1 = vg[base_i + NG], vi2 = vg[base_i + 2 * NG];
    float a0 = 0.f, a1 = 0.f, a2 = 0.f;
#pragma unroll
    for (int e = 0; e < 6; ++e) {
        int off = (e < 3) ? (e - 3) : (e - 2);  // -3,-2,-1,1,2,3
        int j = n + off;
        if (j < 0 || j >= NN) continue;
        int base_j = base_i + off * 3 * NG;
        float d0 = vg[base_j] - vi0;
        float d1 = vg[base_j + NG] - vi1;
        float d2 = vg[base_j + 2 * NG] - vi2;
        float nb = fmaxf(fsqrt(d0 * d0 + d1 * d1 + d2 * d2), EPS);
        float r = frcp(nb);
        a0 = fmaf(d0, r, a0); a1 = fmaf(d1, r, a1); a2 = fmaf(d2, r, a2);
    }
    u[base_i] = a0; u[base_i + NG] = a1; u[base_i + 2 * NG] = a2;
}

// ---------------- K3: edge features + MLPs + dense gate + scatter -----------
__global__ __launch_bounds__(256) void k_main(
    const float* __restrict__ vg, const float* __restrict__ u,
    const float* __restrict__ xs,
    const float* __restrict__ qw1, const float* __restrict__ qb1,
    const float* __restrict__ qw2, const float* __restrict__ qb2,
    const float* __restrict__ kw1, const float* __restrict__ kb1,
    const float* __restrict__ kw2, const float* __restrict__ kb2,
    const float* __restrict__ Wq, const float* __restrict__ bq,
    const float* __restrict__ Wk, const float* __restrict__ bk,
    float* __restrict__ outq, float* __restrict__ outk) {
    __shared__ float ggq[4][6][16];
    __shared__ float ggk[4][6][16];
    __shared__ float mw[2][2][16];   // [qk][featrow][m]
    __shared__ float mb1s[2][16];
    __shared__ float mw2s[2][16];
    __shared__ float mb2s[2];

    int tid = threadIdx.x;
    if (tid < 16) {
        mw[0][0][tid] = qw1[tid]; mw[0][1][tid] = qw1[16 + tid];
        mb1s[0][tid] = qb1[tid];  mw2s[0][tid] = qw2[tid];
        mw[1][0][tid] = kw1[tid]; mw[1][1][tid] = kw1[16 + tid];
        mb1s[1][tid] = kb1[tid];  mw2s[1][tid] = kw2[tid];
    }
    if (tid == 16) { mb2s[0] = qb2[0]; mb2s[1] = kb2[0]; }
    __syncthreads();

    int wave = tid >> 6;
    int lane = tid & 63;
    int eg = lane >> 4, g = lane & 15;
    int bn = blockIdx.x * 4 + wave;             // exact: B*N/4 blocks
    int n = bn & (NN - 1);

    // ---- Phase A: per-edge geometry + MLPs (4 edge-groups x 16 g) ----
    int base_i = (bn * 3) * NG + g;
    float vi0 = vg[base_i], vi1 = vg[base_i + NG], vi2 = vg[base_i + 2 * NG];
    float ui0 = u[base_i],  ui1 = u[base_i + NG],  ui2 = u[base_i + 2 * NG];
    float rnui = frcp(fmaxf(fsqrt(ui0 * ui0 + ui1 * ui1 + ui2 * ui2), EPS));

#pragma unroll
    for (int r = 0; r < 2; ++r) {
        int e = r * 4 + eg;
        if (e < 6) {
            int off = (e < 3) ? (e - 3) : (e - 2);
            int j = n + off;
            if (j >= 0 && j < NN) {
                int base_j = base_i + off * 3 * NG;
                float d0 = vg[base_j] - vi0;
                float d1 = vg[base_j + NG] - vi1;
                float d2 = vg[base_j + 2 * NG] - vi2;
                float rb = frcp(fmaxf(fsqrt(d0 * d0 + d1 * d1 + d2 * d2), EPS));
                float e0 = d0 * rb, e1 = d1 * rb, e2 = d2 * rb;
                float uj0 = u[base_j], uj1 = u[base_j + NG], uj2 = u[base_j + 2 * NG];
                float die = ui0 * e0 + ui1 * e1 + ui2 * e2;
                float ang = fclamp1(die * rnui);
                float p0 = ui0 - die * e0, p1 = ui1 - die * e1, p2 = ui2 - die * e2;
                float dje = uj0 * e0 + uj1 * e1 + uj2 * e2;
                float q0 = uj0 - dje * e0, q1 = uj1 - dje * e1, q2 = uj2 - dje * e2;
                float dp = p0 * q0 + p1 * q1 + p2 * q2;
                float npi = fmaxf(fsqrt(p0 * p0 + p1 * p1 + p2 * p2), EPS);
                float npj = fmaxf(fsqrt(q0 * q0 + q1 * q1 + q2 * q2), EPS);
                float dih = fclamp1(dp * frcp(fmaxf(npi * npj, EPS)));

                float accq = mb2s[0], acck = mb2s[1];
#pragma unroll
                for (int m = 0; m < 16; ++m) {
                    float hq = fmaf(ang, mw[0][0][m], fmaf(dih, mw[0][1][m], mb1s[0][m]));
                    float hk = fmaf(ang, mw[1][0][m], fmaf(dih, mw[1][1][m], mb1s[1][m]));
                    accq = fmaf(fsilu(hq), mw2s[0][m], accq);
                    acck = fmaf(fsilu(hk), mw2s[1][m], acck);
                }
                ggq[wave][e][g] = accq;
                ggk[wave][e][g] = acck;
            }
        }
    }
    __syncthreads();

    // ---- Phase B: dense G->H + sigmoid gate + accumulate over edges ----
    int h0 = lane, h1 = lane + 64;
    float wqr[16][2], wkr[16][2];
#pragma unroll
    for (int gi = 0; gi < 16; ++gi) {
        wqr[gi][0] = Wq[gi * NH + h0]; wqr[gi][1] = Wq[gi * NH + h1];
        wkr[gi][0] = Wk[gi * NH + h0]; wkr[gi][1] = Wk[gi * NH + h1];
    }
    float bq0 = bq[h0], bq1 = bq[h1], bk0 = bk[h0], bk1 = bk[h1];
    float aq0 = 0.f, aq1 = 0.f, ak0 = 0.f, ak1 = 0.f;

#pragma unroll
    for (int e = 0; e < 6; ++e) {
        int off = (e < 3) ? (e - 3) : (e - 2);
        int j = n + off;
        if (j < 0 || j >= NN) continue;
        float sq0 = bq0, sq1 = bq1, sk0 = bk0, sk1 = bk1;
        const float4* gq4 = reinterpret_cast<const float4*>(&ggq[wave][e][0]);
        const float4* gk4 = reinterpret_cast<const float4*>(&ggk[wave][e][0]);
#pragma unroll
        for (int t4 = 0; t4 < 4; ++t4) {
            float4 cq = gq4[t4];
            float4 ck = gk4[t4];
            sq0 = fmaf(cq.x, wqr[t4 * 4 + 0][0], sq0); sq1 = fmaf(cq.x, wqr[t4 * 4 + 0][1], sq1);
            sq0 = fmaf(cq.y, wqr[t4 * 4 + 1][0], sq0); sq1 = fmaf(cq.y, wqr[t4 * 4 + 1][1], sq1);
            sq0 = fmaf(cq.z, wqr[t4 * 4 + 2][0], sq0); sq1 = fmaf(cq.z, wqr[t4 * 4 + 2][1], sq1);
            sq0 = fmaf(cq.w, wqr[t4 * 4 + 3][0], sq0); sq1 = fmaf(cq.w, wqr[t4 * 4 + 3][1], sq1);
            sk0 = fmaf(ck.x, wkr[t4 * 4 + 0][0], sk0); sk1 = fmaf(ck.x, wkr[t4 * 4 + 0][1], sk1);
            sk0 = fmaf(ck.y, wkr[t4 * 4 + 1][0], sk0); sk1 = fmaf(ck.y, wkr[t4 * 4 + 1][1], sk1);
            sk0 = fmaf(ck.z, wkr[t4 * 4 + 2][0], sk0); sk1 = fmaf(ck.z, wkr[t4 * 4 + 2][1], sk1);
            sk0 = fmaf(ck.w, wkr[t4 * 4 + 3][0], sk0); sk1 = fmaf(ck.w, wkr[t4 * 4 + 3][1], sk1);
        }
        int xb = (bn + off) * NH;   // (b*N + j)*H
        float xj0 = xs[xb + h0], xj1 = xs[xb + h1];
        aq0 = fmaf(fsigmoid(sq0), xj0, aq0); aq1 = fmaf(fsigmoid(sq1), xj1, aq1);
        ak0 = fmaf(fsigmoid(sk0), xj0, ak0); ak1 = fmaf(fsigmoid(sk1), xj1, ak1);
    }
    int ob = bn * NH;
    outq[ob + h0] = aq0; outq[ob + h1] = aq1;
    outk[ob + h0] = ak0; outk[ob + h1] = ak1;
}

extern "C" void kernel_launch(void* const* d_in, const int* in_sizes, int n_in,
                              void* d_out, int out_size, void* d_ws, size_t ws_size,
                              hipStream_t stream) {
    const float* xs   = (const float*)d_in[0];
    const float* vec  = (const float*)d_in[1];
    const float* Wg   = (const float*)d_in[2];
    const float* qw1  = (const float*)d_in[3];
    const float* qb1  = (const float*)d_in[4];
    const float* qw2  = (const float*)d_in[5];
    const float* qb2  = (const float*)d_in[6];
    const float* kw1  = (const float*)d_in[7];
    const float* kb1  = (const float*)d_in[8];
    const float* kw2  = (const float*)d_in[9];
    const float* kb2  = (const float*)d_in[10];
    const float* Wq   = (const float*)d_in[11];
    const float* bq   = (const float*)d_in[12];
    const float* Wk   = (const float*)d_in[13];
    const float* bk   = (const float*)d_in[14];

    float* vg = (float*)d_ws;                          // B*N*3*G = 3,145,728 f
    float* u  = vg + (size_t)NB * NN * 3 * NG;         // same size
    float* outq = (float*)d_out;
    float* outk = outq + (size_t)NB * NN * NH;

    // K1: B*N*48 outputs / 256 = 12288 blocks (exact)
    k_vecgeom<<<dim3(12288), dim3(256), 0, stream>>>(vec, Wg, vg);
    // K2: B*N*16 threads / 256 = 4096 blocks (exact)
    k_u<<<dim3(4096), dim3(256), 0, stream>>>(vg, u);
    // K3: B*N nodes, 4 per block = 16384 blocks (exact)
    k_main<<<dim3(16384), dim3(256), 0, stream>>>(
        vg, u, xs, qw1, qb1, qw2, qb2, kw1, kb1, kw2, kb2,
        Wq, bq, Wk, bk, outq, outk);
}